// Round 21
// baseline (51.613 us; speedup 1.0000x reference)
//
#include <hip/hip_runtime.h>
#include <hip/hip_bf16.h>

// InferenceLinear: out[m][n] = sum_k x[m][k] * (q[n][k]*qrange[n][k/256] + qmin[n][k/256])
// M=512, N=2048, K=4096, 16 groups of 256.
// R21: delete the partials round-trip (33.5MB write + 33.5MB read + reduce
// kernel ~11us) via XCD-LOCAL atomics: all 8 k-slices of each 128x128 tile run
// on the SAME XCD (decode: xcd=b&7, kc=(b>>3)&7, tile=b>>6; n-panel = 2*xcd +
// tile>>2). Tile outputs (512KB/XCD) stay L2-resident; RMW never crosses XCDs
// (R10's pathology was kc==XCD: 8 contenders on 8 different XCDs). GEMM body =
// champion (8 waves 2x4, 64x32 wave tiles, gload_lds w/ inverse-swizzled src,
// 2 barriers/tile). NT hints reverted (R20: harmful). Pipeline: pack -> GEMM
// (atomicAdd into memset-zeroed out).

#define M_T 512
#define N_T 2048
#define K_T 4096
#define NGRP 16
#define BM 128
#define BN 128
#define BK 64
#define OUT_ELEMS (M_T * N_T)
#define W_ELEMS (N_T * K_T)          // 8388608 bf16
#define X_ELEMS (M_T * K_T)          // 2097152 bf16

typedef __attribute__((ext_vector_type(8))) short mfrag_t;           // 8 bf16 (4 VGPR)
typedef __attribute__((ext_vector_type(8))) unsigned short u16x8;
typedef __attribute__((ext_vector_type(4))) float f32x4;

__device__ __forceinline__ unsigned short f2bf(float f) {
  union { __hip_bfloat16 h; unsigned short u; } c;
  c.h = __float2bfloat16(f);
  return c.u;
}

// ---- pass 1: dequant W (int32 q -> bf16) + cast X (fp32 -> bf16) ----
__global__ __launch_bounds__(256) void pack_kernel(
    const float* __restrict__ x, const int* __restrict__ qw,
    const float* __restrict__ qrange, const float* __restrict__ qmin,
    unsigned short* __restrict__ wsW, unsigned short* __restrict__ wsX) {
  const int bid = blockIdx.x;
  const int tid = threadIdx.x;
  if (bid < (W_ELEMS / 8) / 256) {
    const int gidx = bid * 256 + tid;        // [0, 1048576)
    const int o = gidx >> 9;                 // 512 groups-of-8 per row
    const int k8 = gidx & 511;
    const int g = k8 >> 5;                   // 32 groups-of-8 per quant group
    const float sc = qrange[o * NGRP + g];
    const float mn = qmin[o * NGRP + g];
    const int4* q = (const int4*)(qw + ((size_t)o << 12) + (k8 << 3));
    const int4 q0 = q[0], q1 = q[1];
    u16x8 p;
    p[0] = f2bf((float)q0.x * sc + mn); p[1] = f2bf((float)q0.y * sc + mn);
    p[2] = f2bf((float)q0.z * sc + mn); p[3] = f2bf((float)q0.w * sc + mn);
    p[4] = f2bf((float)q1.x * sc + mn); p[5] = f2bf((float)q1.y * sc + mn);
    p[6] = f2bf((float)q1.z * sc + mn); p[7] = f2bf((float)q1.w * sc + mn);
    *(u16x8*)(wsW + ((size_t)gidx << 3)) = p;
  } else {
    const int gidx = (bid - (W_ELEMS / 8) / 256) * 256 + tid;  // [0, 262144)
    const float4* a = (const float4*)(x + ((size_t)gidx << 3));
    const float4 a0 = a[0], a1 = a[1];
    u16x8 p;
    p[0] = f2bf(a0.x); p[1] = f2bf(a0.y); p[2] = f2bf(a0.z); p[3] = f2bf(a0.w);
    p[4] = f2bf(a1.x); p[5] = f2bf(a1.y); p[6] = f2bf(a1.z); p[7] = f2bf(a1.w);
    *(u16x8*)(wsX + ((size_t)gidx << 3)) = p;
  }
}

// ---- pass 2: bf16 GEMM, gload_lds staging, XCD-local atomic epilogue ----
template <int KSPLIT>
__global__ __launch_bounds__(512, 4) void dq_gemm_kernel(
    const unsigned short* __restrict__ wsX, const unsigned short* __restrict__ wsW,
    float* __restrict__ out) {
  constexpr int KC = K_T / KSPLIT;
  constexpr int NTC = KC / BK;

  // physical layout: [row][slot^(row&7)], slot = 8-elem (16B) unit; linear fill
  __shared__ __align__(16) unsigned short As[BM * BK];
  __shared__ __align__(16) unsigned short Bs[BN * BK];

  const int tid = threadIdx.x;
  // XCD-local split-K decode: all 8 kc of a tile on ONE XCD.
  const int b = blockIdx.x;
  const int xcd = b & 7;
  const int kc = (b >> 3) & 7;          // k-chunk
  const int tile = b >> 6;              // 0..7
  const int mt = tile & 3;              // m-tile 0..3
  const int nt = 2 * xcd + (tile >> 2); // n-tile 0..15, 2 panels per XCD
  const int n0 = nt * BN;
  const int m0 = mt * BM;
  const int kbase = kc * KC;

  // compute mapping: 8 waves, 2(M) x 4(N); wave tile 64x32
  const int lane = tid & 63;
  const int wv = tid >> 6;
  const int wm = (wv >> 2) * 64;   // 0,64
  const int wn = (wv & 3) * 32;    // 0,32,64,96
  const int lr = lane & 15;
  const int lq = lane >> 4;
  const int rxl = lr & 7;  // read-side xor (row&7 == lr&7: wm,wn,f*16 mult of 8)

  // staging mapping for global_load_lds (16B/lane): wave wv covers rows
  // [wv*16, wv*16+16) in two 1KB chunks (8 rows each). lane l -> row += l>>3,
  // phys slot = l&7. LDS[row][p] holds logical data[p ^ (row&7)]; row&7 == l>>3,
  // so per-lane GLOBAL source col16 = (l&7) ^ (l>>3). Dest linear = base+lane*16.
  const int swzcol = (((lane & 7) ^ (lane >> 3)) << 3);       // elem offset
  const int r0 = wv * 16 + (lane >> 3);                        // chunk0 row
  const int r1 = r0 + 8;                                       // chunk1 row
  const unsigned short* gA0 = wsX + (size_t)(m0 + r0) * K_T + kbase + swzcol;
  const unsigned short* gA1 = wsX + (size_t)(m0 + r1) * K_T + kbase + swzcol;
  const unsigned short* gB0 = wsW + (size_t)(n0 + r0) * K_T + kbase + swzcol;
  const unsigned short* gB1 = wsW + (size_t)(n0 + r1) * K_T + kbase + swzcol;
  unsigned short* lA0 = &As[wv * 1024];        // elems; 2KB per wave
  unsigned short* lA1 = &As[wv * 1024 + 512];
  unsigned short* lB0 = &Bs[wv * 1024];
  unsigned short* lB1 = &Bs[wv * 1024 + 512];

#define STAGE(T)                                                              \
  do {                                                                        \
    const size_t o_ = (size_t)(T) * BK;                                       \
    __builtin_amdgcn_global_load_lds(                                         \
        (const __attribute__((address_space(1))) void*)(gA0 + o_),            \
        (__attribute__((address_space(3))) void*)lA0, 16, 0, 0);              \
    __builtin_amdgcn_global_load_lds(                                         \
        (const __attribute__((address_space(1))) void*)(gA1 + o_),            \
        (__attribute__((address_space(3))) void*)lA1, 16, 0, 0);              \
    __builtin_amdgcn_global_load_lds(                                         \
        (const __attribute__((address_space(1))) void*)(gB0 + o_),            \
        (__attribute__((address_space(3))) void*)lB0, 16, 0, 0);              \
    __builtin_amdgcn_global_load_lds(                                         \
        (const __attribute__((address_space(1))) void*)(gB1 + o_),            \
        (__attribute__((address_space(3))) void*)lB1, 16, 0, 0);              \
  } while (0)

  f32x4 acc[4][2] = {};

  STAGE(0);
  for (int t = 0; t < NTC; ++t) {
    __syncthreads();  // drains vmcnt(0): staged tile visible to all waves

#pragma unroll
    for (int kk = 0; kk < 2; ++kk) {
      const int so = ((kk * 4 + lq) ^ rxl) << 3;
      mfrag_t af[4], bf[2];
#pragma unroll
      for (int fm = 0; fm < 4; ++fm)
        af[fm] = *(const mfrag_t*)&As[(wm + fm * 16 + lr) * BK + so];
#pragma unroll
      for (int fn = 0; fn < 2; ++fn)
        bf[fn] = *(const mfrag_t*)&Bs[(wn + fn * 16 + lr) * BK + so];
#pragma unroll
      for (int fm = 0; fm < 4; ++fm)
#pragma unroll
        for (int fn = 0; fn < 2; ++fn)
          acc[fm][fn] = __builtin_amdgcn_mfma_f32_16x16x32_bf16(af[fm], bf[fn], acc[fm][fn], 0, 0, 0);
    }

    if (t + 1 < NTC) {
      __syncthreads();  // all waves done reading before overwrite
      STAGE(t + 1);
    }
  }
#undef STAGE

  // ---- epilogue: XCD-local atomicAdd into zeroed out ----
  // C/D layout col=lane&15, row=(lane>>4)*4+reg (measured m89/m91)
#pragma unroll
  for (int fm = 0; fm < 4; ++fm) {
#pragma unroll
    for (int fn = 0; fn < 2; ++fn) {
      const int rr = m0 + wm + fm * 16 + lq * 4;
      const int c = n0 + wn + fn * 16 + lr;
      float* op = out + (size_t)rr * N_T + c;
      atomicAdd(op + 0 * (size_t)N_T, acc[fm][fn][0]);
      atomicAdd(op + 1 * (size_t)N_T, acc[fm][fn][1]);
      atomicAdd(op + 2 * (size_t)N_T, acc[fm][fn][2]);
      atomicAdd(op + 3 * (size_t)N_T, acc[fm][fn][3]);
    }
  }
}

// ---- fallback only (never expected to run): naive dot per output elem ----
__global__ void naive_kernel(const float* __restrict__ x, const int* __restrict__ qw,
                             const float* __restrict__ qrange, const float* __restrict__ qmin,
                             float* __restrict__ out) {
  const int idx = blockIdx.x * 256 + threadIdx.x;
  if (idx >= OUT_ELEMS) return;
  const int m = idx / N_T, n = idx % N_T;
  float s = 0.f;
  for (int g = 0; g < NGRP; ++g) {
    const float sc = qrange[n * NGRP + g], mn = qmin[n * NGRP + g];
    float d = 0.f, xs = 0.f;
    for (int k = g * 256; k < (g + 1) * 256; ++k) {
      d += x[(size_t)m * K_T + k] * (float)qw[(size_t)n * K_T + k];
      xs += x[(size_t)m * K_T + k];
    }
    s += d * sc + xs * mn;
  }
  out[idx] = s;
}

extern "C" void kernel_launch(void* const* d_in, const int* in_sizes, int n_in,
                              void* d_out, int out_size, void* d_ws, size_t ws_size,
                              hipStream_t stream) {
  const float* x = (const float*)d_in[0];
  const int* qw = (const int*)d_in[1];
  const float* qr = (const float*)d_in[2];
  const float* qm = (const float*)d_in[3];
  float* out = (float*)d_out;

  constexpr int KS = 8;
  unsigned short* wsW = (unsigned short*)d_ws;
  unsigned short* wsX = wsW + W_ELEMS;
  const size_t need = (size_t)W_ELEMS * 2 + (size_t)X_ELEMS * 2;
  if (ws_size >= need) {
    const int packblk = (W_ELEMS / 8) / 256 + (X_ELEMS / 8) / 256;  // 4096+1024
    pack_kernel<<<packblk, 256, 0, stream>>>(x, qw, qr, qm, wsW, wsX);
    hipMemsetAsync(out, 0, (size_t)OUT_ELEMS * sizeof(float), stream);
    const int nblk = (N_T / BN) * (M_T / BM) * KS;  // 512
    dq_gemm_kernel<KS><<<nblk, dim3(512, 1, 1), 0, stream>>>(wsX, wsW, out);
  } else {
    naive_kernel<<<(OUT_ELEMS + 255) / 256, 256, 0, stream>>>(x, qw, qr, qm, out);
  }
}

// Round 22
// 32.239 us; speedup vs baseline: 1.6009x; 1.6009x over previous
//
#include <hip/hip_runtime.h>
#include <hip/hip_bf16.h>

// InferenceLinear: out[m][n] = sum_k x[m][k] * (q[n][k]*qrange[n][k/256] + qmin[n][k/256])
// M=512, N=2048, K=4096, 16 groups of 256.
// R22: bf16 partials. Atomics definitively dead (R4/R10/R21: +15-20us at any
// placement); partials round-trip (67MB HBM ~ 10us) halved by storing split-K
// partials as bf16 (K=512 partial std~13, bf16 err ~0.05/slice, 8 slices
// -> ~0.15 << 3.66 threshold). Structure = R14 champion: pack -> bf16 GEMM
// (gload_lds, 128x128, BK=64, KSPLIT=8, XCD decode kc=b&7) -> reduce (bf16 in,
// fp32 accumulate+out, deterministic order).

#define M_T 512
#define N_T 2048
#define K_T 4096
#define NGRP 16
#define BM 128
#define BN 128
#define BK 64
#define OUT_ELEMS (M_T * N_T)
#define W_ELEMS (N_T * K_T)          // 8388608 bf16
#define X_ELEMS (M_T * K_T)          // 2097152 bf16

typedef __attribute__((ext_vector_type(8))) short mfrag_t;           // 8 bf16 (4 VGPR)
typedef __attribute__((ext_vector_type(8))) unsigned short u16x8;
typedef __attribute__((ext_vector_type(4))) float f32x4;

__device__ __forceinline__ unsigned short f2bf(float f) {
  union { __hip_bfloat16 h; unsigned short u; } c;
  c.h = __float2bfloat16(f);
  return c.u;
}

__device__ __forceinline__ float bf2f(unsigned short u) {
  union { unsigned int i; float f; } c;
  c.i = ((unsigned int)u) << 16;
  return c.f;
}

// ---- pass 1: dequant W (int32 q -> bf16) + cast X (fp32 -> bf16) ----
__global__ __launch_bounds__(256) void pack_kernel(
    const float* __restrict__ x, const int* __restrict__ qw,
    const float* __restrict__ qrange, const float* __restrict__ qmin,
    unsigned short* __restrict__ wsW, unsigned short* __restrict__ wsX) {
  const int bid = blockIdx.x;
  const int tid = threadIdx.x;
  if (bid < (W_ELEMS / 8) / 256) {
    const int gidx = bid * 256 + tid;        // [0, 1048576)
    const int o = gidx >> 9;                 // 512 groups-of-8 per row
    const int k8 = gidx & 511;
    const int g = k8 >> 5;                   // 32 groups-of-8 per quant group
    const float sc = qrange[o * NGRP + g];
    const float mn = qmin[o * NGRP + g];
    const int4* q = (const int4*)(qw + ((size_t)o << 12) + (k8 << 3));
    const int4 q0 = q[0], q1 = q[1];
    u16x8 p;
    p[0] = f2bf((float)q0.x * sc + mn); p[1] = f2bf((float)q0.y * sc + mn);
    p[2] = f2bf((float)q0.z * sc + mn); p[3] = f2bf((float)q0.w * sc + mn);
    p[4] = f2bf((float)q1.x * sc + mn); p[5] = f2bf((float)q1.y * sc + mn);
    p[6] = f2bf((float)q1.z * sc + mn); p[7] = f2bf((float)q1.w * sc + mn);
    *(u16x8*)(wsW + ((size_t)gidx << 3)) = p;
  } else {
    const int gidx = (bid - (W_ELEMS / 8) / 256) * 256 + tid;  // [0, 262144)
    const float4* a = (const float4*)(x + ((size_t)gidx << 3));
    const float4 a0 = a[0], a1 = a[1];
    u16x8 p;
    p[0] = f2bf(a0.x); p[1] = f2bf(a0.y); p[2] = f2bf(a0.z); p[3] = f2bf(a0.w);
    p[4] = f2bf(a1.x); p[5] = f2bf(a1.y); p[6] = f2bf(a1.z); p[7] = f2bf(a1.w);
    *(u16x8*)(wsX + ((size_t)gidx << 3)) = p;
  }
}

// ---- pass 2: bf16 GEMM with global_load_lds staging; bf16 partial stores ----
template <int KSPLIT, bool XCDSWZ>
__global__ __launch_bounds__(512, 4) void dq_gemm_kernel(
    const unsigned short* __restrict__ wsX, const unsigned short* __restrict__ wsW,
    unsigned short* __restrict__ dst) {
  constexpr int KC = K_T / KSPLIT;
  constexpr int NTC = KC / BK;

  // physical layout: [row][slot^(row&7)], slot = 8-elem (16B) unit; linear fill
  __shared__ __align__(16) unsigned short As[BM * BK];
  __shared__ __align__(16) unsigned short Bs[BN * BK];

  const int tid = threadIdx.x;
  int xt, yt, kc;
  if (XCDSWZ) {
    const int b = blockIdx.x;
    kc = b & 7;                 // XCD id == k-chunk (assumes b%8 round-robin)
    const int slot = b >> 3;
    xt = slot & 15;             // n-tile
    yt = slot >> 4;             // m-tile
  } else {
    const int b = blockIdx.x;
    xt = b & 15;
    yt = (b >> 4) & 3;
    kc = b >> 6;
  }
  const int n0 = xt * BN;
  const int m0 = yt * BM;
  const int kbase = kc * KC;

  // compute mapping: 8 waves, 2(M) x 4(N); wave tile 64x32
  const int lane = tid & 63;
  const int wv = tid >> 6;
  const int wm = (wv >> 2) * 64;   // 0,64
  const int wn = (wv & 3) * 32;    // 0,32,64,96
  const int lr = lane & 15;
  const int lq = lane >> 4;
  const int rxl = lr & 7;  // read-side xor (row&7 == lr&7: wm,wn,f*16 mult of 8)

  // staging mapping for global_load_lds (16B/lane): wave wv covers rows
  // [wv*16, wv*16+16) in two 1KB chunks (8 rows each). lane l -> row += l>>3,
  // phys slot = l&7. LDS[row][p] holds logical data[p ^ (row&7)]; row&7 == l>>3,
  // so per-lane GLOBAL source col16 = (l&7) ^ (l>>3). Dest linear = base+lane*16.
  const int swzcol = (((lane & 7) ^ (lane >> 3)) << 3);       // elem offset
  const int r0 = wv * 16 + (lane >> 3);                        // chunk0 row
  const int r1 = r0 + 8;                                       // chunk1 row
  const unsigned short* gA0 = wsX + (size_t)(m0 + r0) * K_T + kbase + swzcol;
  const unsigned short* gA1 = wsX + (size_t)(m0 + r1) * K_T + kbase + swzcol;
  const unsigned short* gB0 = wsW + (size_t)(n0 + r0) * K_T + kbase + swzcol;
  const unsigned short* gB1 = wsW + (size_t)(n0 + r1) * K_T + kbase + swzcol;
  unsigned short* lA0 = &As[wv * 1024];        // elems; 2KB per wave
  unsigned short* lA1 = &As[wv * 1024 + 512];
  unsigned short* lB0 = &Bs[wv * 1024];
  unsigned short* lB1 = &Bs[wv * 1024 + 512];

#define STAGE(T)                                                              \
  do {                                                                        \
    const size_t o_ = (size_t)(T) * BK;                                       \
    __builtin_amdgcn_global_load_lds(                                         \
        (const __attribute__((address_space(1))) void*)(gA0 + o_),            \
        (__attribute__((address_space(3))) void*)lA0, 16, 0, 0);              \
    __builtin_amdgcn_global_load_lds(                                         \
        (const __attribute__((address_space(1))) void*)(gA1 + o_),            \
        (__attribute__((address_space(3))) void*)lA1, 16, 0, 0);              \
    __builtin_amdgcn_global_load_lds(                                         \
        (const __attribute__((address_space(1))) void*)(gB0 + o_),            \
        (__attribute__((address_space(3))) void*)lB0, 16, 0, 0);              \
    __builtin_amdgcn_global_load_lds(                                         \
        (const __attribute__((address_space(1))) void*)(gB1 + o_),            \
        (__attribute__((address_space(3))) void*)lB1, 16, 0, 0);              \
  } while (0)

  f32x4 acc[4][2] = {};

  STAGE(0);
  for (int t = 0; t < NTC; ++t) {
    __syncthreads();  // drains vmcnt(0): staged tile visible to all waves

#pragma unroll
    for (int kk = 0; kk < 2; ++kk) {
      const int so = ((kk * 4 + lq) ^ rxl) << 3;
      mfrag_t af[4], bf[2];
#pragma unroll
      for (int fm = 0; fm < 4; ++fm)
        af[fm] = *(const mfrag_t*)&As[(wm + fm * 16 + lr) * BK + so];
#pragma unroll
      for (int fn = 0; fn < 2; ++fn)
        bf[fn] = *(const mfrag_t*)&Bs[(wn + fn * 16 + lr) * BK + so];
#pragma unroll
      for (int fm = 0; fm < 4; ++fm)
#pragma unroll
        for (int fn = 0; fn < 2; ++fn)
          acc[fm][fn] = __builtin_amdgcn_mfma_f32_16x16x32_bf16(af[fm], bf[fn], acc[fm][fn], 0, 0, 0);
    }

    if (t + 1 < NTC) {
      __syncthreads();  // all waves done reading before overwrite
      STAGE(t + 1);
    }
  }
#undef STAGE

  // ---- epilogue: bf16 partial stores to ws slice (half the bytes) ----
  // C/D layout col=lane&15, row=(lane>>4)*4+reg (measured m89/m91)
  unsigned short* base = dst + (size_t)kc * OUT_ELEMS;
#pragma unroll
  for (int fm = 0; fm < 4; ++fm) {
#pragma unroll
    for (int fn = 0; fn < 2; ++fn) {
      const int rr = m0 + wm + fm * 16 + lq * 4;
      const int c = n0 + wn + fn * 16 + lr;
      unsigned short* op = base + (size_t)rr * N_T + c;
      op[0 * (size_t)N_T] = f2bf(acc[fm][fn][0]);
      op[1 * (size_t)N_T] = f2bf(acc[fm][fn][1]);
      op[2 * (size_t)N_T] = f2bf(acc[fm][fn][2]);
      op[3 * (size_t)N_T] = f2bf(acc[fm][fn][3]);
    }
  }
}

// ---- pass 3: out[i] = sum_s bf16 partials[s][i], fp32 accum, fixed order ----
template <int KSPLIT>
__global__ __launch_bounds__(256) void reduce_kernel(const unsigned short* __restrict__ ws,
                                                     float* __restrict__ out) {
  const int i8 = blockIdx.x * 256 + threadIdx.x;   // 8 elems per thread
  const size_t base = (size_t)i8 * 8;
  float s[8];
  {
    const u16x8 v = *(const u16x8*)(ws + base);
#pragma unroll
    for (int j = 0; j < 8; ++j) s[j] = bf2f(v[j]);
  }
#pragma unroll
  for (int sl = 1; sl < KSPLIT; ++sl) {
    const u16x8 v = *(const u16x8*)(ws + (size_t)sl * OUT_ELEMS + base);
#pragma unroll
    for (int j = 0; j < 8; ++j) s[j] += bf2f(v[j]);
  }
  float4* o = (float4*)(out + base);
  o[0] = make_float4(s[0], s[1], s[2], s[3]);
  o[1] = make_float4(s[4], s[5], s[6], s[7]);
}

// ---- fallback only (never expected to run): naive dot per output elem ----
__global__ void naive_kernel(const float* __restrict__ x, const int* __restrict__ qw,
                             const float* __restrict__ qrange, const float* __restrict__ qmin,
                             float* __restrict__ out) {
  const int idx = blockIdx.x * 256 + threadIdx.x;
  if (idx >= OUT_ELEMS) return;
  const int m = idx / N_T, n = idx % N_T;
  float s = 0.f;
  for (int g = 0; g < NGRP; ++g) {
    const float sc = qrange[n * NGRP + g], mn = qmin[n * NGRP + g];
    float d = 0.f, xs = 0.f;
    for (int k = g * 256; k < (g + 1) * 256; ++k) {
      d += x[(size_t)m * K_T + k] * (float)qw[(size_t)n * K_T + k];
      xs += x[(size_t)m * K_T + k];
    }
    s += d * sc + xs * mn;
  }
  out[idx] = s;
}

extern "C" void kernel_launch(void* const* d_in, const int* in_sizes, int n_in,
                              void* d_out, int out_size, void* d_ws, size_t ws_size,
                              hipStream_t stream) {
  const float* x = (const float*)d_in[0];
  const int* qw = (const int*)d_in[1];
  const float* qr = (const float*)d_in[2];
  const float* qm = (const float*)d_in[3];
  float* out = (float*)d_out;

  constexpr int KS = 8;
  unsigned short* wsW = (unsigned short*)d_ws;
  unsigned short* wsX = wsW + W_ELEMS;
  unsigned short* partials = wsX + X_ELEMS;
  const size_t need = (size_t)W_ELEMS * 2 + (size_t)X_ELEMS * 2 +
                      (size_t)KS * OUT_ELEMS * 2;
  if (ws_size >= need) {
    const int packblk = (W_ELEMS / 8) / 256 + (X_ELEMS / 8) / 256;  // 4096+1024
    pack_kernel<<<packblk, 256, 0, stream>>>(x, qw, qr, qm, wsW, wsX);
    const int nblk = (N_T / BN) * (M_T / BM) * KS;  // 512
    dq_gemm_kernel<KS, true><<<nblk, dim3(512, 1, 1), 0, stream>>>(wsX, wsW, partials);
    reduce_kernel<KS><<<OUT_ELEMS / 8 / 256, 256, 0, stream>>>(partials, out);
  } else {
    naive_kernel<<<(OUT_ELEMS + 255) / 256, 256, 0, stream>>>(x, qw, qr, qm, out);
  }
}